// Round 7
// baseline (129.875 us; speedup 1.0000x reference)
//
#include <hip/hip_runtime.h>

#define SK 8192
#define SQ 8192
#define DD 128
#define ZSPLIT 8

typedef __attribute__((ext_vector_type(8))) short short8;
typedef __attribute__((ext_vector_type(4))) float f32x4;
typedef __attribute__((ext_vector_type(4))) unsigned uint4v;
typedef unsigned short ushort_t;

// round-to-nearest-even f32 -> bf16
__device__ __forceinline__ unsigned short f2bf(float x){
  unsigned int u = __float_as_uint(x);
  u += 0x7FFFu + ((u >> 16) & 1u);
  return (unsigned short)(u >> 16);
}

// async global->LDS DMA, 16B/lane. LDS dest = uniform base + lane*16.
__device__ __forceinline__ void gld16(const void* g, void* l){
  __builtin_amdgcn_global_load_lds(
      (const __attribute__((address_space(1))) unsigned int*)g,
      (__attribute__((address_space(3))) unsigned int*)l, 16, 0, 0);
}

// ---------------------------------------------------------------------------
// prep_kq: cast K (pre-scaled by log2(e)/sqrt(128)) and Q to bf16, stored as
// pre-swizzled 64-row tile images (row stride 256B, 16B-slot XOR swizzle):
// element (row r, d): byte = r*256 + (((d>>3)*16) ^ ((r&7)<<4)) + (d&7)*2
// ---------------------------------------------------------------------------
__global__ __launch_bounds__(256) void prep_kq(const float* __restrict__ Kp,
                                               const float* __restrict__ Qp,
                                               ushort_t* __restrict__ kws,
                                               ushort_t* __restrict__ qws){
  int g = blockIdx.x*256 + threadIdx.x;
  int arr = g >> 17;
  int s   = g & 131071;
  int row = s >> 4;
  int c16 = s & 15;
  const float* src = (arr ? Qp : Kp) + row*DD + c16*8;
  const float scale = arr ? 1.0f : 0.12751743f;   // log2(e)/sqrt(128)
  float4 f0 = ((const float4*)src)[0];
  float4 f1 = ((const float4*)src)[1];
  unsigned int wv[4];
  wv[0] = (unsigned)f2bf(f0.x*scale) | ((unsigned)f2bf(f0.y*scale) << 16);
  wv[1] = (unsigned)f2bf(f0.z*scale) | ((unsigned)f2bf(f0.w*scale) << 16);
  wv[2] = (unsigned)f2bf(f1.x*scale) | ((unsigned)f2bf(f1.y*scale) << 16);
  wv[3] = (unsigned)f2bf(f1.z*scale) | ((unsigned)f2bf(f1.w*scale) << 16);
  ushort_t* base = arr ? qws : kws;
  int tile = row >> 6, r = row & 63;
  char* dst = (char*)(base + (size_t)tile*8192) + r*256 + ((c16*16) ^ ((r&7)<<4));
  ((uint4*)dst)[0] = make_uint4(wv[0],wv[1],wv[2],wv[3]);
}

// ---------------------------------------------------------------------------
// kz: per-column stats (unchanged — passing since r5). Waves specialize
// to k-rows; Q B-frags in regs; K dbuf via global_load_lds; 1 barrier/iter.
// ---------------------------------------------------------------------------
__global__ __launch_bounds__(256, 4) void kz(const ushort_t* __restrict__ kws,
                                             const ushort_t* __restrict__ qws,
                                             float* __restrict__ zpart){
  __shared__ __align__(16) char smem[33792];   // K dbuf 2x16KB | zred 1KB
  int wg = blockIdx.x;            // 1024
  int qs   = wg >> 3;             // 0..127 (64-q stripe)
  int kspl = wg & 7;
  int t = threadIdx.x, lane = t & 63, w = t >> 6;   // w in 0..3
  int r15 = lane & 15, g4 = lane >> 4;
  int sw = (r15 & 7) << 4;

  { const char* kg = (const char*)kws + (size_t)(kspl*16)*16384;
    #pragma unroll
    for (int i=0;i<4;i++)
      gld16(kg + (t + i*256)*16, smem + (t + i*256)*16);
  }
  short8 qf[4][4];
  { const char* qg = (const char*)qws + (size_t)qs*16384;
    #pragma unroll
    for (int qg_=0; qg_<4; ++qg_)
      #pragma unroll
      for (int kk=0; kk<4; ++kk)
        qf[qg_][kk] = *(const short8*)(qg + (qg_*16 + r15)*256 + ((kk*64 + g4*16) ^ sw));
  }
  __syncthreads();

  float zac0=0.f, zac1=0.f, zac2=0.f, zac3=0.f;
  for (int it=0; it<16; ++it){
    if (it+1 < 16){
      const char* kg = (const char*)kws + (size_t)(kspl*16+it+1)*16384;
      char* dst = smem + ((it+1)&1)*16384;
      #pragma unroll
      for (int i=0;i<4;i++)
        gld16(kg + (t + i*256)*16, dst + (t + i*256)*16);
    }
    const char* Kb = smem + (it&1)*16384;
    short8 ak[4];
    #pragma unroll
    for (int kk=0;kk<4;kk++)
      ak[kk] = *(const short8*)(Kb + (w*16 + r15)*256 + ((kk*64 + g4*16) ^ sw));
    f32x4 s0={0,0,0,0}, s1={0,0,0,0}, s2={0,0,0,0}, s3={0,0,0,0};
    #pragma unroll
    for (int kk=0; kk<4; ++kk){
      s0 = __builtin_amdgcn_mfma_f32_16x16x32_bf16(ak[kk], qf[0][kk], s0, 0, 0, 0);
      s1 = __builtin_amdgcn_mfma_f32_16x16x32_bf16(ak[kk], qf[1][kk], s1, 0, 0, 0);
      s2 = __builtin_amdgcn_mfma_f32_16x16x32_bf16(ak[kk], qf[2][kk], s2, 0, 0, 0);
      s3 = __builtin_amdgcn_mfma_f32_16x16x32_bf16(ak[kk], qf[3][kk], s3, 0, 0, 0);
    }
    #pragma unroll
    for (int j=0;j<4;j++){
      zac0 += __builtin_exp2f(s0[j]);
      zac1 += __builtin_exp2f(s1[j]);
      zac2 += __builtin_exp2f(s2[j]);
      zac3 += __builtin_exp2f(s3[j]);
    }
    __syncthreads();
  }
  zac0 += __shfl_xor(zac0,16); zac0 += __shfl_xor(zac0,32);
  zac1 += __shfl_xor(zac1,16); zac1 += __shfl_xor(zac1,32);
  zac2 += __shfl_xor(zac2,16); zac2 += __shfl_xor(zac2,32);
  zac3 += __shfl_xor(zac3,16); zac3 += __shfl_xor(zac3,32);
  float* zred = (float*)(smem + 32768);
  if (lane < 16){
    zred[w*64 + 0*16 + lane] = zac0;
    zred[w*64 + 1*16 + lane] = zac1;
    zred[w*64 + 2*16 + lane] = zac2;
    zred[w*64 + 3*16 + lane] = zac3;
  }
  __syncthreads();
  if (t < 64){
    float z = zred[t] + zred[64+t] + zred[128+t] + zred[192+t];
    zpart[(size_t)kspl*SQ + qs*64 + t] = z;
  }
}

// ---------------------------------------------------------------------------
// prep_v: runs AFTER kz. Vt[q,:] = V[q,:] / Z_q, stored as SWIZZLED V^T tile
// images: per 64-q tile, [128 dv][64 q] bf16:
// byte = dv*128 + (((q>>3)*16) ^ ((dv&7)<<4)) + (q&7)*2
// ---------------------------------------------------------------------------
__global__ __launch_bounds__(256) void prep_v(const float* __restrict__ Vp,
                                              const float* __restrict__ zpart,
                                              ushort_t* __restrict__ vtws){
  __shared__ ushort_t vl[64][132];
  int tile = blockIdx.x;    // 0..127
  int t = threadIdx.x;
  int q = t >> 2, dvb = (t & 3)*32;
  float z = 0.f;
  #pragma unroll
  for (int s=0;s<ZSPLIT;s++) z += zpart[(size_t)s*SQ + tile*64 + q];
  float vinv = 1.0f / z;
  const float* src = Vp + (size_t)(tile*64 + q)*DD + dvb;
  #pragma unroll
  for (int j=0;j<8;j++){
    float4 f = ((const float4*)src)[j];
    vl[q][dvb + j*4 + 0] = f2bf(f.x*vinv);
    vl[q][dvb + j*4 + 1] = f2bf(f.y*vinv);
    vl[q][dvb + j*4 + 2] = f2bf(f.z*vinv);
    vl[q][dvb + j*4 + 3] = f2bf(f.w*vinv);
  }
  __syncthreads();
  char* obase = (char*)(vtws + (size_t)tile*8192);
  #pragma unroll
  for (int s2=0;s2<4;s2++){
    int sid = t*4 + s2;
    int dv = sid >> 3, qs = sid & 7;
    unsigned int wv[4];
    #pragma unroll
    for (int p=0;p<4;p++){
      unsigned lo = vl[qs*8 + p*2 + 0][dv];
      unsigned hi = vl[qs*8 + p*2 + 1][dv];
      wv[p] = lo | (hi << 16);
    }
    char* dst = obase + dv*128 + ((qs*16) ^ ((dv&7)<<4));
    ((uint4*)dst)[0] = make_uint4(wv[0],wv[1],wv[2],wv[3]);
  }
}

// ---------------------------------------------------------------------------
// ko: fused main pass. Same math/layouts as round 6 (proven), new schedule:
// single-buffered 32KB LDS (Q 16K + V 16K), 2 barriers/iter, grid =
// 64 ktiles x 16 qsp = 1024 WGs x 256 thr -> 4 blocks/CU x 4 waves =
// 16 waves/CU (4/SIMD from 4 independent blocks: cross-block TLP hides
// the stage/vmcnt/barrier phase). Wave owns 32 k-rows (kf[2][4]); each
// Q/V LDS read feeds two MFMAs.
// ---------------------------------------------------------------------------
__global__ __launch_bounds__(256, 4) void ko(const ushort_t* __restrict__ kws,
                                             const ushort_t* __restrict__ qws,
                                             const ushort_t* __restrict__ vtws,
                                             float* __restrict__ out){
  __shared__ __align__(16) char smem[32768];
  int wg = blockIdx.x;            // 1024
  int ktile = wg >> 4;            // 0..63  (128 k-rows)
  int qsp   = wg & 15;            // 0..15  (8 q-tiles of 64)
  int t = threadIdx.x, lane = t & 63, w = t >> 6;   // w in 0..3
  int r15 = lane & 15, g4 = lane >> 4;
  int sw = (r15 & 7) << 4;

  // ---- prologue: stage K (32KB) into smem, hoist kf, then Q0/V0 ----
  { const char* kg = (const char*)kws + (size_t)ktile*32768;
    #pragma unroll
    for (int i=0;i<8;i++)
      gld16(kg + (t + i*256)*16, smem + (t + i*256)*16);
  }
  __syncthreads();
  short8 kf[2][4];
  #pragma unroll
  for (int b=0;b<2;b++){
    int r = w*32 + b*16 + r15;
    const char* kb = smem + (r>>6)*16384 + (r&63)*256;
    #pragma unroll
    for (int kk=0;kk<4;kk++)
      kf[b][kk] = *(const short8*)(kb + ((kk*64 + g4*16) ^ sw));
  }
  __syncthreads();
  { const char* qg = (const char*)qws  + (size_t)(qsp*8)*16384;
    const char* vg = (const char*)vtws + (size_t)(qsp*8)*16384;
    #pragma unroll
    for (int i=0;i<4;i++){
      gld16(qg + (t + i*256)*16, smem + (t + i*256)*16);
      gld16(vg + (t + i*256)*16, smem + 16384 + (t + i*256)*16);
    }
  }
  __syncthreads();

  f32x4 zero = {0.f,0.f,0.f,0.f};
  f32x4 acc[2][8];
  #pragma unroll
  for (int b=0;b<2;b++)
    #pragma unroll
    for (int i=0;i<8;i++) acc[b][i] = zero;

  for (int it=0; it<8; ++it){
    const char* Qb = smem;
    const char* Vb = smem + 16384;
    // ---- G1: S^T for both k-blocks, exp2, pack, redistribute ----
    short8 af[2][2];                 // [qc][b]
    #pragma unroll
    for (int qc=0; qc<2; ++qc){
      unsigned pw[2][4];
      #pragma unroll
      for (int blk=0; blk<2; ++blk){
        f32x4 s0 = {0.f,0.f,0.f,0.f};
        f32x4 s1 = {0.f,0.f,0.f,0.f};
        #pragma unroll
        for (int kk=0; kk<4; ++kk){
          int qrow = qc*32 + blk*16 + r15;
          short8 aq = *(const short8*)(Qb + qrow*256 + ((kk*64 + g4*16) ^ sw));
          s0 = __builtin_amdgcn_mfma_f32_16x16x32_bf16(aq, kf[0][kk], s0, 0, 0, 0);
          s1 = __builtin_amdgcn_mfma_f32_16x16x32_bf16(aq, kf[1][kk], s1, 0, 0, 0);
        }
        #pragma unroll
        for (int b=0;b<2;b++){
          f32x4 s = b ? s1 : s0;
          float p0 = __builtin_exp2f(s[0]);
          float p1 = __builtin_exp2f(s[1]);
          float p2 = __builtin_exp2f(s[2]);
          float p3 = __builtin_exp2f(s[3]);
          unsigned wa, wb;
          asm("v_cvt_pk_bf16_f32 %0, %1, %2" : "=v"(wa) : "v"(p0), "v"(p1));
          asm("v_cvt_pk_bf16_f32 %0, %1, %2" : "=v"(wb) : "v"(p2), "v"(p3));
          pw[b][blk*2+0] = wa;
          pw[b][blk*2+1] = wb;
        }
      }
      #pragma unroll
      for (int b=0;b<2;b++){
        asm("v_permlane32_swap_b32 %0, %1" : "+v"(pw[b][0]), "+v"(pw[b][2]));
        asm("v_permlane32_swap_b32 %0, %1" : "+v"(pw[b][1]), "+v"(pw[b][3]));
        asm("v_permlane16_swap_b32 %0, %1" : "+v"(pw[b][0]), "+v"(pw[b][2]));
        asm("v_permlane16_swap_b32 %0, %1" : "+v"(pw[b][1]), "+v"(pw[b][3]));
        uint4v fw = { pw[b][0], pw[b][1], pw[b][2], pw[b][3] };
        af[qc][b] = __builtin_bit_cast(short8, fw);
      }
    }
    // ---- PV: O += P~.V~ (each vb read feeds both k-blocks) ----
    #pragma unroll
    for (int dvb=0; dvb<8; ++dvb){
      int dv = dvb*16 + r15;
      #pragma unroll
      for (int qc=0; qc<2; ++qc){
        short8 bv = *(const short8*)(Vb + dv*128 + (((qc*4 + g4)*16) ^ sw));
        acc[0][dvb] = __builtin_amdgcn_mfma_f32_16x16x32_bf16(af[qc][0], bv, acc[0][dvb], 0, 0, 0);
        acc[1][dvb] = __builtin_amdgcn_mfma_f32_16x16x32_bf16(af[qc][1], bv, acc[1][dvb], 0, 0, 0);
      }
    }
    // ---- re-stage buffer for next q-tile ----
    if (it+1 < 8){
      __syncthreads();               // all waves done reading buf
      const char* qg = (const char*)qws  + (size_t)(qsp*8+it+1)*16384;
      const char* vg = (const char*)vtws + (size_t)(qsp*8+it+1)*16384;
      #pragma unroll
      for (int i=0;i<4;i++){
        gld16(qg + (t + i*256)*16, smem + (t + i*256)*16);
        gld16(vg + (t + i*256)*16, smem + 16384 + (t + i*256)*16);
      }
      __syncthreads();               // vmcnt(0) drained before release
    }
  }
  // ---- epilogue: accumulate across the 16 q-split WGs ----
  #pragma unroll
  for (int b=0;b<2;b++)
    #pragma unroll
    for (int dvb=0; dvb<8; ++dvb)
      #pragma unroll
      for (int j=0;j<4;j++){
        int k  = ktile*128 + w*32 + b*16 + g4*4 + j;
        int dv = dvb*16 + r15;
        atomicAdd(out + (size_t)k*DD + dv, acc[b][dvb][j]);
      }
}

extern "C" void kernel_launch(void* const* d_in, const int* in_sizes, int n_in,
                              void* d_out, int out_size, void* d_ws, size_t ws_size,
                              hipStream_t stream) {
  const float* Kp = (const float*)d_in[0];
  const float* Qp = (const float*)d_in[1];
  const float* Vp = (const float*)d_in[2];
  float* out = (float*)d_out;
  char* ws = (char*)d_ws;
  ushort_t* kws  = (ushort_t*)ws;
  ushort_t* qws  = (ushort_t*)(ws + ((size_t)2<<20));
  ushort_t* vtws = (ushort_t*)(ws + ((size_t)4<<20));
  float* zpart   = (float*)(ws + ((size_t)6<<20));

  hipMemsetAsync(d_out, 0, (size_t)SK*DD*sizeof(float), stream);
  prep_kq<<<dim3(1024), dim3(256), 0, stream>>>(Kp, Qp, kws, qws);
  kz     <<<dim3(1024), dim3(256), 0, stream>>>(kws, qws, zpart);
  prep_v <<<dim3(128),  dim3(256), 0, stream>>>(Vp, zpart, vtws);
  ko     <<<dim3(1024), dim3(256), 0, stream>>>(kws, qws, vtws, out);
}

// Round 8
// 120.719 us; speedup vs baseline: 1.0758x; 1.0758x over previous
//
#include <hip/hip_runtime.h>

#define SK 8192
#define SQ 8192
#define DD 128
#define ZSPLIT 8

typedef __attribute__((ext_vector_type(8))) short short8;
typedef __attribute__((ext_vector_type(4))) float f32x4;
typedef __attribute__((ext_vector_type(4))) unsigned uint4v;
typedef unsigned short ushort_t;

// round-to-nearest-even f32 -> bf16
__device__ __forceinline__ unsigned short f2bf(float x){
  unsigned int u = __float_as_uint(x);
  u += 0x7FFFu + ((u >> 16) & 1u);
  return (unsigned short)(u >> 16);
}

// async global->LDS DMA, 16B/lane. LDS dest = uniform base + lane*16.
__device__ __forceinline__ void gld16(const void* g, void* l){
  __builtin_amdgcn_global_load_lds(
      (const __attribute__((address_space(1))) unsigned int*)g,
      (__attribute__((address_space(3))) unsigned int*)l, 16, 0, 0);
}

// ---------------------------------------------------------------------------
// prep_kq: cast K (pre-scaled by log2(e)/sqrt(128)) and Q to bf16, stored as
// pre-swizzled 64-row tile images (row stride 256B, 16B-slot XOR swizzle):
// element (row r, d): byte = r*256 + (((d>>3)*16) ^ ((r&7)<<4)) + (d&7)*2
// ---------------------------------------------------------------------------
__global__ __launch_bounds__(256) void prep_kq(const float* __restrict__ Kp,
                                               const float* __restrict__ Qp,
                                               ushort_t* __restrict__ kws,
                                               ushort_t* __restrict__ qws){
  int g = blockIdx.x*256 + threadIdx.x;
  int arr = g >> 17;
  int s   = g & 131071;
  int row = s >> 4;
  int c16 = s & 15;
  const float* src = (arr ? Qp : Kp) + row*DD + c16*8;
  const float scale = arr ? 1.0f : 0.12751743f;   // log2(e)/sqrt(128)
  float4 f0 = ((const float4*)src)[0];
  float4 f1 = ((const float4*)src)[1];
  unsigned int wv[4];
  wv[0] = (unsigned)f2bf(f0.x*scale) | ((unsigned)f2bf(f0.y*scale) << 16);
  wv[1] = (unsigned)f2bf(f0.z*scale) | ((unsigned)f2bf(f0.w*scale) << 16);
  wv[2] = (unsigned)f2bf(f1.x*scale) | ((unsigned)f2bf(f1.y*scale) << 16);
  wv[3] = (unsigned)f2bf(f1.z*scale) | ((unsigned)f2bf(f1.w*scale) << 16);
  ushort_t* base = arr ? qws : kws;
  int tile = row >> 6, r = row & 63;
  char* dst = (char*)(base + (size_t)tile*8192) + r*256 + ((c16*16) ^ ((r&7)<<4));
  ((uint4*)dst)[0] = make_uint4(wv[0],wv[1],wv[2],wv[3]);
}

// ---------------------------------------------------------------------------
// kz: per-column stats (unchanged — passing since r5). Waves specialize
// to k-rows; Q B-frags in regs; K dbuf via global_load_lds; 1 barrier/iter.
// ---------------------------------------------------------------------------
__global__ __launch_bounds__(256, 4) void kz(const ushort_t* __restrict__ kws,
                                             const ushort_t* __restrict__ qws,
                                             float* __restrict__ zpart){
  __shared__ __align__(16) char smem[33792];   // K dbuf 2x16KB | zred 1KB
  int wg = blockIdx.x;            // 1024
  int qs   = wg >> 3;             // 0..127 (64-q stripe)
  int kspl = wg & 7;
  int t = threadIdx.x, lane = t & 63, w = t >> 6;   // w in 0..3
  int r15 = lane & 15, g4 = lane >> 4;
  int sw = (r15 & 7) << 4;

  { const char* kg = (const char*)kws + (size_t)(kspl*16)*16384;
    #pragma unroll
    for (int i=0;i<4;i++)
      gld16(kg + (t + i*256)*16, smem + (t + i*256)*16);
  }
  short8 qf[4][4];
  { const char* qg = (const char*)qws + (size_t)qs*16384;
    #pragma unroll
    for (int qg_=0; qg_<4; ++qg_)
      #pragma unroll
      for (int kk=0; kk<4; ++kk)
        qf[qg_][kk] = *(const short8*)(qg + (qg_*16 + r15)*256 + ((kk*64 + g4*16) ^ sw));
  }
  __syncthreads();

  float zac0=0.f, zac1=0.f, zac2=0.f, zac3=0.f;
  for (int it=0; it<16; ++it){
    if (it+1 < 16){
      const char* kg = (const char*)kws + (size_t)(kspl*16+it+1)*16384;
      char* dst = smem + ((it+1)&1)*16384;
      #pragma unroll
      for (int i=0;i<4;i++)
        gld16(kg + (t + i*256)*16, dst + (t + i*256)*16);
    }
    const char* Kb = smem + (it&1)*16384;
    short8 ak[4];
    #pragma unroll
    for (int kk=0;kk<4;kk++)
      ak[kk] = *(const short8*)(Kb + (w*16 + r15)*256 + ((kk*64 + g4*16) ^ sw));
    f32x4 s0={0,0,0,0}, s1={0,0,0,0}, s2={0,0,0,0}, s3={0,0,0,0};
    #pragma unroll
    for (int kk=0; kk<4; ++kk){
      s0 = __builtin_amdgcn_mfma_f32_16x16x32_bf16(ak[kk], qf[0][kk], s0, 0, 0, 0);
      s1 = __builtin_amdgcn_mfma_f32_16x16x32_bf16(ak[kk], qf[1][kk], s1, 0, 0, 0);
      s2 = __builtin_amdgcn_mfma_f32_16x16x32_bf16(ak[kk], qf[2][kk], s2, 0, 0, 0);
      s3 = __builtin_amdgcn_mfma_f32_16x16x32_bf16(ak[kk], qf[3][kk], s3, 0, 0, 0);
    }
    #pragma unroll
    for (int j=0;j<4;j++){
      zac0 += __builtin_exp2f(s0[j]);
      zac1 += __builtin_exp2f(s1[j]);
      zac2 += __builtin_exp2f(s2[j]);
      zac3 += __builtin_exp2f(s3[j]);
    }
    __syncthreads();
  }
  zac0 += __shfl_xor(zac0,16); zac0 += __shfl_xor(zac0,32);
  zac1 += __shfl_xor(zac1,16); zac1 += __shfl_xor(zac1,32);
  zac2 += __shfl_xor(zac2,16); zac2 += __shfl_xor(zac2,32);
  zac3 += __shfl_xor(zac3,16); zac3 += __shfl_xor(zac3,32);
  float* zred = (float*)(smem + 32768);
  if (lane < 16){
    zred[w*64 + 0*16 + lane] = zac0;
    zred[w*64 + 1*16 + lane] = zac1;
    zred[w*64 + 2*16 + lane] = zac2;
    zred[w*64 + 3*16 + lane] = zac3;
  }
  __syncthreads();
  if (t < 64){
    float z = zred[t] + zred[64+t] + zred[128+t] + zred[192+t];
    zpart[(size_t)kspl*SQ + qs*64 + t] = z;
  }
}

// ---------------------------------------------------------------------------
// prep_v: runs AFTER kz. Vt[q,:] = V[q,:] / Z_q, stored as SWIZZLED V^T tile
// images: per 64-q tile, [128 dv][64 q] bf16:
// byte = dv*128 + (((q>>3)*16) ^ ((dv&7)<<4)) + (q&7)*2
// ---------------------------------------------------------------------------
__global__ __launch_bounds__(256) void prep_v(const float* __restrict__ Vp,
                                              const float* __restrict__ zpart,
                                              ushort_t* __restrict__ vtws){
  __shared__ ushort_t vl[64][132];
  int tile = blockIdx.x;    // 0..127
  int t = threadIdx.x;
  int q = t >> 2, dvb = (t & 3)*32;
  float z = 0.f;
  #pragma unroll
  for (int s=0;s<ZSPLIT;s++) z += zpart[(size_t)s*SQ + tile*64 + q];
  float vinv = 1.0f / z;
  const float* src = Vp + (size_t)(tile*64 + q)*DD + dvb;
  #pragma unroll
  for (int j=0;j<8;j++){
    float4 f = ((const float4*)src)[j];
    vl[q][dvb + j*4 + 0] = f2bf(f.x*vinv);
    vl[q][dvb + j*4 + 1] = f2bf(f.y*vinv);
    vl[q][dvb + j*4 + 2] = f2bf(f.z*vinv);
    vl[q][dvb + j*4 + 3] = f2bf(f.w*vinv);
  }
  __syncthreads();
  char* obase = (char*)(vtws + (size_t)tile*8192);
  #pragma unroll
  for (int s2=0;s2<4;s2++){
    int sid = t*4 + s2;
    int dv = sid >> 3, qs = sid & 7;
    unsigned int wv[4];
    #pragma unroll
    for (int p=0;p<4;p++){
      unsigned lo = vl[qs*8 + p*2 + 0][dv];
      unsigned hi = vl[qs*8 + p*2 + 1][dv];
      wv[p] = lo | (hi << 16);
    }
    char* dst = obase + dv*128 + ((qs*16) ^ ((dv&7)<<4));
    ((uint4*)dst)[0] = make_uint4(wv[0],wv[1],wv[2],wv[3]);
  }
}

// ---------------------------------------------------------------------------
// ko: fused main pass — r7 schedule with ONE change: XCD-coherent WG map.
// wgid = qsp*64 + ktile  ->  wgid%8 = ktile%8, so all 16 q-split WGs that
// atomically accumulate the same 64KB out-tile land on the SAME XCD: the
// atomic RMW lines stay resident in that XCD's L2 instead of write-through
// ping-pong between non-coherent L2s (r7: WRITE_SIZE 87MB). K-tile reads
// also become XCD-local.
// ---------------------------------------------------------------------------
__global__ __launch_bounds__(256, 4) void ko(const ushort_t* __restrict__ kws,
                                             const ushort_t* __restrict__ qws,
                                             const ushort_t* __restrict__ vtws,
                                             float* __restrict__ out){
  __shared__ __align__(16) char smem[32768];
  int wg = blockIdx.x;            // 1024
  int ktile = wg & 63;            // 0..63  (128 k-rows); xcd = ktile%8
  int qsp   = wg >> 6;            // 0..15  (8 q-tiles of 64)
  int t = threadIdx.x, lane = t & 63, w = t >> 6;   // w in 0..3
  int r15 = lane & 15, g4 = lane >> 4;
  int sw = (r15 & 7) << 4;

  // ---- prologue: stage K (32KB) into smem, hoist kf, then Q0/V0 ----
  { const char* kg = (const char*)kws + (size_t)ktile*32768;
    #pragma unroll
    for (int i=0;i<8;i++)
      gld16(kg + (t + i*256)*16, smem + (t + i*256)*16);
  }
  __syncthreads();
  short8 kf[2][4];
  #pragma unroll
  for (int b=0;b<2;b++){
    int r = w*32 + b*16 + r15;
    const char* kb = smem + (r>>6)*16384 + (r&63)*256;
    #pragma unroll
    for (int kk=0;kk<4;kk++)
      kf[b][kk] = *(const short8*)(kb + ((kk*64 + g4*16) ^ sw));
  }
  __syncthreads();
  { const char* qg = (const char*)qws  + (size_t)(qsp*8)*16384;
    const char* vg = (const char*)vtws + (size_t)(qsp*8)*16384;
    #pragma unroll
    for (int i=0;i<4;i++){
      gld16(qg + (t + i*256)*16, smem + (t + i*256)*16);
      gld16(vg + (t + i*256)*16, smem + 16384 + (t + i*256)*16);
    }
  }
  __syncthreads();

  f32x4 zero = {0.f,0.f,0.f,0.f};
  f32x4 acc[2][8];
  #pragma unroll
  for (int b=0;b<2;b++)
    #pragma unroll
    for (int i=0;i<8;i++) acc[b][i] = zero;

  for (int it=0; it<8; ++it){
    const char* Qb = smem;
    const char* Vb = smem + 16384;
    // ---- G1: S^T for both k-blocks, exp2, pack, redistribute ----
    short8 af[2][2];                 // [qc][b]
    #pragma unroll
    for (int qc=0; qc<2; ++qc){
      unsigned pw[2][4];
      #pragma unroll
      for (int blk=0; blk<2; ++blk){
        f32x4 s0 = {0.f,0.f,0.f,0.f};
        f32x4 s1 = {0.f,0.f,0.f,0.f};
        #pragma unroll
        for (int kk=0; kk<4; ++kk){
          int qrow = qc*32 + blk*16 + r15;
          short8 aq = *(const short8*)(Qb + qrow*256 + ((kk*64 + g4*16) ^ sw));
          s0 = __builtin_amdgcn_mfma_f32_16x16x32_bf16(aq, kf[0][kk], s0, 0, 0, 0);
          s1 = __builtin_amdgcn_mfma_f32_16x16x32_bf16(aq, kf[1][kk], s1, 0, 0, 0);
        }
        #pragma unroll
        for (int b=0;b<2;b++){
          f32x4 s = b ? s1 : s0;
          float p0 = __builtin_exp2f(s[0]);
          float p1 = __builtin_exp2f(s[1]);
          float p2 = __builtin_exp2f(s[2]);
          float p3 = __builtin_exp2f(s[3]);
          unsigned wa, wb;
          asm("v_cvt_pk_bf16_f32 %0, %1, %2" : "=v"(wa) : "v"(p0), "v"(p1));
          asm("v_cvt_pk_bf16_f32 %0, %1, %2" : "=v"(wb) : "v"(p2), "v"(p3));
          pw[b][blk*2+0] = wa;
          pw[b][blk*2+1] = wb;
        }
      }
      #pragma unroll
      for (int b=0;b<2;b++){
        asm("v_permlane32_swap_b32 %0, %1" : "+v"(pw[b][0]), "+v"(pw[b][2]));
        asm("v_permlane32_swap_b32 %0, %1" : "+v"(pw[b][1]), "+v"(pw[b][3]));
        asm("v_permlane16_swap_b32 %0, %1" : "+v"(pw[b][0]), "+v"(pw[b][2]));
        asm("v_permlane16_swap_b32 %0, %1" : "+v"(pw[b][1]), "+v"(pw[b][3]));
        uint4v fw = { pw[b][0], pw[b][1], pw[b][2], pw[b][3] };
        af[qc][b] = __builtin_bit_cast(short8, fw);
      }
    }
    // ---- PV: O += P~.V~ (each vb read feeds both k-blocks) ----
    #pragma unroll
    for (int dvb=0; dvb<8; ++dvb){
      int dv = dvb*16 + r15;
      #pragma unroll
      for (int qc=0; qc<2; ++qc){
        short8 bv = *(const short8*)(Vb + dv*128 + (((qc*4 + g4)*16) ^ sw));
        acc[0][dvb] = __builtin_amdgcn_mfma_f32_16x16x32_bf16(af[qc][0], bv, acc[0][dvb], 0, 0, 0);
        acc[1][dvb] = __builtin_amdgcn_mfma_f32_16x16x32_bf16(af[qc][1], bv, acc[1][dvb], 0, 0, 0);
      }
    }
    // ---- re-stage buffer for next q-tile ----
    if (it+1 < 8){
      __syncthreads();               // all waves done reading buf
      const char* qg = (const char*)qws  + (size_t)(qsp*8+it+1)*16384;
      const char* vg = (const char*)vtws + (size_t)(qsp*8+it+1)*16384;
      #pragma unroll
      for (int i=0;i<4;i++){
        gld16(qg + (t + i*256)*16, smem + (t + i*256)*16);
        gld16(vg + (t + i*256)*16, smem + 16384 + (t + i*256)*16);
      }
      __syncthreads();               // vmcnt(0) drained before release
    }
  }
  // ---- epilogue: accumulate across the 16 q-split WGs (XCD-local) ----
  #pragma unroll
  for (int b=0;b<2;b++)
    #pragma unroll
    for (int dvb=0; dvb<8; ++dvb)
      #pragma unroll
      for (int j=0;j<4;j++){
        int k  = ktile*128 + w*32 + b*16 + g4*4 + j;
        int dv = dvb*16 + r15;
        atomicAdd(out + (size_t)k*DD + dv, acc[b][dvb][j]);
      }
}

extern "C" void kernel_launch(void* const* d_in, const int* in_sizes, int n_in,
                              void* d_out, int out_size, void* d_ws, size_t ws_size,
                              hipStream_t stream) {
  const float* Kp = (const float*)d_in[0];
  const float* Qp = (const float*)d_in[1];
  const float* Vp = (const float*)d_in[2];
  float* out = (float*)d_out;
  char* ws = (char*)d_ws;
  ushort_t* kws  = (ushort_t*)ws;
  ushort_t* qws  = (ushort_t*)(ws + ((size_t)2<<20));
  ushort_t* vtws = (ushort_t*)(ws + ((size_t)4<<20));
  float* zpart   = (float*)(ws + ((size_t)6<<20));

  hipMemsetAsync(d_out, 0, (size_t)SK*DD*sizeof(float), stream);
  prep_kq<<<dim3(1024), dim3(256), 0, stream>>>(Kp, Qp, kws, qws);
  kz     <<<dim3(1024), dim3(256), 0, stream>>>(kws, qws, zpart);
  prep_v <<<dim3(128),  dim3(256), 0, stream>>>(Vp, zpart, vtws);
  ko     <<<dim3(1024), dim3(256), 0, stream>>>(kws, qws, vtws, out);
}

// Round 9
// 101.742 us; speedup vs baseline: 1.2765x; 1.1865x over previous
//
#include <hip/hip_runtime.h>

#define SK 8192
#define SQ 8192
#define DD 128
#define ZSPLIT 8

typedef __attribute__((ext_vector_type(8))) short short8;
typedef __attribute__((ext_vector_type(4))) float f32x4;
typedef __attribute__((ext_vector_type(4))) unsigned uint4v;
typedef unsigned short ushort_t;

// round-to-nearest-even f32 -> bf16
__device__ __forceinline__ unsigned short f2bf(float x){
  unsigned int u = __float_as_uint(x);
  u += 0x7FFFu + ((u >> 16) & 1u);
  return (unsigned short)(u >> 16);
}

// async global->LDS DMA, 16B/lane. LDS dest = uniform base + lane*16.
__device__ __forceinline__ void gld16(const void* g, void* l){
  __builtin_amdgcn_global_load_lds(
      (const __attribute__((address_space(1))) unsigned int*)g,
      (__attribute__((address_space(3))) unsigned int*)l, 16, 0, 0);
}

// ---------------------------------------------------------------------------
// prep_kq: cast K (pre-scaled by log2(e)/sqrt(128)) and Q to bf16, stored as
// pre-swizzled 64-row tile images (row stride 256B, 16B-slot XOR swizzle):
// element (row r, d): byte = r*256 + (((d>>3)*16) ^ ((r&7)<<4)) + (d&7)*2
// ---------------------------------------------------------------------------
__global__ __launch_bounds__(256) void prep_kq(const float* __restrict__ Kp,
                                               const float* __restrict__ Qp,
                                               ushort_t* __restrict__ kws,
                                               ushort_t* __restrict__ qws){
  int g = blockIdx.x*256 + threadIdx.x;
  int arr = g >> 17;
  int s   = g & 131071;
  int row = s >> 4;
  int c16 = s & 15;
  const float* src = (arr ? Qp : Kp) + row*DD + c16*8;
  const float scale = arr ? 1.0f : 0.12751743f;   // log2(e)/sqrt(128)
  float4 f0 = ((const float4*)src)[0];
  float4 f1 = ((const float4*)src)[1];
  unsigned int wv[4];
  wv[0] = (unsigned)f2bf(f0.x*scale) | ((unsigned)f2bf(f0.y*scale) << 16);
  wv[1] = (unsigned)f2bf(f0.z*scale) | ((unsigned)f2bf(f0.w*scale) << 16);
  wv[2] = (unsigned)f2bf(f1.x*scale) | ((unsigned)f2bf(f1.y*scale) << 16);
  wv[3] = (unsigned)f2bf(f1.z*scale) | ((unsigned)f2bf(f1.w*scale) << 16);
  ushort_t* base = arr ? qws : kws;
  int tile = row >> 6, r = row & 63;
  char* dst = (char*)(base + (size_t)tile*8192) + r*256 + ((c16*16) ^ ((r&7)<<4));
  ((uint4*)dst)[0] = make_uint4(wv[0],wv[1],wv[2],wv[3]);
}

// ---------------------------------------------------------------------------
// kz: per-column stats (unchanged — passing since r5). Waves specialize
// to k-rows; Q B-frags in regs; K dbuf via global_load_lds; 1 barrier/iter.
// ---------------------------------------------------------------------------
__global__ __launch_bounds__(256, 4) void kz(const ushort_t* __restrict__ kws,
                                             const ushort_t* __restrict__ qws,
                                             float* __restrict__ zpart){
  __shared__ __align__(16) char smem[33792];   // K dbuf 2x16KB | zred 1KB
  int wg = blockIdx.x;            // 1024
  int qs   = wg >> 3;             // 0..127 (64-q stripe)
  int kspl = wg & 7;
  int t = threadIdx.x, lane = t & 63, w = t >> 6;   // w in 0..3
  int r15 = lane & 15, g4 = lane >> 4;
  int sw = (r15 & 7) << 4;

  { const char* kg = (const char*)kws + (size_t)(kspl*16)*16384;
    #pragma unroll
    for (int i=0;i<4;i++)
      gld16(kg + (t + i*256)*16, smem + (t + i*256)*16);
  }
  short8 qf[4][4];
  { const char* qg = (const char*)qws + (size_t)qs*16384;
    #pragma unroll
    for (int qg_=0; qg_<4; ++qg_)
      #pragma unroll
      for (int kk=0; kk<4; ++kk)
        qf[qg_][kk] = *(const short8*)(qg + (qg_*16 + r15)*256 + ((kk*64 + g4*16) ^ sw));
  }
  __syncthreads();

  float zac0=0.f, zac1=0.f, zac2=0.f, zac3=0.f;
  for (int it=0; it<16; ++it){
    if (it+1 < 16){
      const char* kg = (const char*)kws + (size_t)(kspl*16+it+1)*16384;
      char* dst = smem + ((it+1)&1)*16384;
      #pragma unroll
      for (int i=0;i<4;i++)
        gld16(kg + (t + i*256)*16, dst + (t + i*256)*16);
    }
    const char* Kb = smem + (it&1)*16384;
    short8 ak[4];
    #pragma unroll
    for (int kk=0;kk<4;kk++)
      ak[kk] = *(const short8*)(Kb + (w*16 + r15)*256 + ((kk*64 + g4*16) ^ sw));
    f32x4 s0={0,0,0,0}, s1={0,0,0,0}, s2={0,0,0,0}, s3={0,0,0,0};
    #pragma unroll
    for (int kk=0; kk<4; ++kk){
      s0 = __builtin_amdgcn_mfma_f32_16x16x32_bf16(ak[kk], qf[0][kk], s0, 0, 0, 0);
      s1 = __builtin_amdgcn_mfma_f32_16x16x32_bf16(ak[kk], qf[1][kk], s1, 0, 0, 0);
      s2 = __builtin_amdgcn_mfma_f32_16x16x32_bf16(ak[kk], qf[2][kk], s2, 0, 0, 0);
      s3 = __builtin_amdgcn_mfma_f32_16x16x32_bf16(ak[kk], qf[3][kk], s3, 0, 0, 0);
    }
    #pragma unroll
    for (int j=0;j<4;j++){
      zac0 += __builtin_exp2f(s0[j]);
      zac1 += __builtin_exp2f(s1[j]);
      zac2 += __builtin_exp2f(s2[j]);
      zac3 += __builtin_exp2f(s3[j]);
    }
    __syncthreads();
  }
  zac0 += __shfl_xor(zac0,16); zac0 += __shfl_xor(zac0,32);
  zac1 += __shfl_xor(zac1,16); zac1 += __shfl_xor(zac1,32);
  zac2 += __shfl_xor(zac2,16); zac2 += __shfl_xor(zac2,32);
  zac3 += __shfl_xor(zac3,16); zac3 += __shfl_xor(zac3,32);
  float* zred = (float*)(smem + 32768);
  if (lane < 16){
    zred[w*64 + 0*16 + lane] = zac0;
    zred[w*64 + 1*16 + lane] = zac1;
    zred[w*64 + 2*16 + lane] = zac2;
    zred[w*64 + 3*16 + lane] = zac3;
  }
  __syncthreads();
  if (t < 64){
    float z = zred[t] + zred[64+t] + zred[128+t] + zred[192+t];
    zpart[(size_t)kspl*SQ + qs*64 + t] = z;
  }
}

// ---------------------------------------------------------------------------
// prep_v: runs AFTER kz. Vt[q,:] = V[q,:] / Z_q, stored as SWIZZLED V^T tile
// images: per 64-q tile, [128 dv][64 q] bf16:
// byte = dv*128 + (((q>>3)*16) ^ ((dv&7)<<4)) + (q&7)*2
// ---------------------------------------------------------------------------
__global__ __launch_bounds__(256) void prep_v(const float* __restrict__ Vp,
                                              const float* __restrict__ zpart,
                                              ushort_t* __restrict__ vtws){
  __shared__ ushort_t vl[64][132];
  int tile = blockIdx.x;    // 0..127
  int t = threadIdx.x;
  int q = t >> 2, dvb = (t & 3)*32;
  float z = 0.f;
  #pragma unroll
  for (int s=0;s<ZSPLIT;s++) z += zpart[(size_t)s*SQ + tile*64 + q];
  float vinv = 1.0f / z;
  const float* src = Vp + (size_t)(tile*64 + q)*DD + dvb;
  #pragma unroll
  for (int j=0;j<8;j++){
    float4 f = ((const float4*)src)[j];
    vl[q][dvb + j*4 + 0] = f2bf(f.x*vinv);
    vl[q][dvb + j*4 + 1] = f2bf(f.y*vinv);
    vl[q][dvb + j*4 + 2] = f2bf(f.z*vinv);
    vl[q][dvb + j*4 + 3] = f2bf(f.w*vinv);
  }
  __syncthreads();
  char* obase = (char*)(vtws + (size_t)tile*8192);
  #pragma unroll
  for (int s2=0;s2<4;s2++){
    int sid = t*4 + s2;
    int dv = sid >> 3, qs = sid & 7;
    unsigned int wv[4];
    #pragma unroll
    for (int p=0;p<4;p++){
      unsigned lo = vl[qs*8 + p*2 + 0][dv];
      unsigned hi = vl[qs*8 + p*2 + 1][dv];
      wv[p] = lo | (hi << 16);
    }
    char* dst = obase + dv*128 + ((qs*16) ^ ((dv&7)<<4));
    ((uint4*)dst)[0] = make_uint4(wv[0],wv[1],wv[2],wv[3]);
  }
}

// ---------------------------------------------------------------------------
// ko: r6's proven schedule (64KB dbuf, stage-early, 1 barrier/iter, 2:1
// MFMA:LDS-read) at DOUBLE residency: 512 thr = 8 waves = 4 k-groups x
// 2 q-halves -> 16 waves/CU. Wave (kg,qh): 32 k-rows vs its 32-q half;
// all fragment math identical to r6 with qc := qh. Q-half pair shares an
// out-tile: epilogue LDS-reduces the pair, then qh=0 waves issue the
// atomics (volume stays 8.4M = r6 level). XCD-coherent WG map.
// ---------------------------------------------------------------------------
__global__ __launch_bounds__(512, 4) void ko(const ushort_t* __restrict__ kws,
                                             const ushort_t* __restrict__ qws,
                                             const ushort_t* __restrict__ vtws,
                                             float* __restrict__ out){
  __shared__ __align__(16) char smem[65536];   // dbuf 2 x (Q 16K + V 16K)
  int wg = blockIdx.x;            // 512
  int ktile = wg & 63;            // xcd = ktile%8: qsp-mates share an XCD
  int qsp   = wg >> 6;            // 0..7
  int t = threadIdx.x, lane = t & 63, w = t >> 6;   // w in 0..7
  int kg = w & 3, qh = w >> 2;
  int r15 = lane & 15, g4 = lane >> 4;
  int sw = (r15 & 7) << 4;

  // ---- prologue: stage K (32KB), hoist kf, then Q0/V0 into buf0 ----
  { const char* kgp = (const char*)kws + (size_t)ktile*32768;
    #pragma unroll
    for (int i=0;i<4;i++)
      gld16(kgp + (t + i*512)*16, smem + (t + i*512)*16);
  }
  __syncthreads();
  short8 kf[2][4];
  #pragma unroll
  for (int b=0;b<2;b++){
    int r = kg*32 + b*16 + r15;
    const char* kb = smem + (r>>6)*16384 + (r&63)*256;
    #pragma unroll
    for (int kk=0;kk<4;kk++)
      kf[b][kk] = *(const short8*)(kb + ((kk*64 + g4*16) ^ sw));
  }
  __syncthreads();
  { const char* qg = (const char*)qws  + (size_t)(qsp*16)*16384;
    const char* vg = (const char*)vtws + (size_t)(qsp*16)*16384;
    #pragma unroll
    for (int i=0;i<2;i++){
      gld16(qg + (t + i*512)*16, smem + (t + i*512)*16);
      gld16(vg + (t + i*512)*16, smem + 16384 + (t + i*512)*16);
    }
  }

  f32x4 zero = {0.f,0.f,0.f,0.f};
  f32x4 acc[2][8];
  #pragma unroll
  for (int b=0;b<2;b++)
    #pragma unroll
    for (int i=0;i<8;i++) acc[b][i] = zero;

  for (int it=0; it<16; ++it){
    __syncthreads();                 // buf(it) DMA drained; buf(it^1) free
    const char* Qb = smem + (it&1)*32768;
    const char* Vb = Qb + 16384;
    // prefetch next Q/V into other buffer (drained at next barrier)
    if (it+1 < 16){
      const char* qg = (const char*)qws  + (size_t)(qsp*16+it+1)*16384;
      const char* vg = (const char*)vtws + (size_t)(qsp*16+it+1)*16384;
      char* dst = smem + ((it+1)&1)*32768;
      #pragma unroll
      for (int i=0;i<2;i++){
        gld16(qg + (t + i*512)*16, dst + (t + i*512)*16);
        gld16(vg + (t + i*512)*16, dst + 16384 + (t + i*512)*16);
      }
    }
    // ---- G1: S^T for wave's q-half x both k-blocks ----
    unsigned pw[2][4];
    #pragma unroll
    for (int blk=0; blk<2; ++blk){
      f32x4 s0 = {0.f,0.f,0.f,0.f};
      f32x4 s1 = {0.f,0.f,0.f,0.f};
      #pragma unroll
      for (int kk=0; kk<4; ++kk){
        int qrow = qh*32 + blk*16 + r15;
        short8 aq = *(const short8*)(Qb + qrow*256 + ((kk*64 + g4*16) ^ sw));
        s0 = __builtin_amdgcn_mfma_f32_16x16x32_bf16(aq, kf[0][kk], s0, 0, 0, 0);
        s1 = __builtin_amdgcn_mfma_f32_16x16x32_bf16(aq, kf[1][kk], s1, 0, 0, 0);
      }
      #pragma unroll
      for (int b=0;b<2;b++){
        f32x4 s = b ? s1 : s0;
        float p0 = __builtin_exp2f(s[0]);
        float p1 = __builtin_exp2f(s[1]);
        float p2 = __builtin_exp2f(s[2]);
        float p3 = __builtin_exp2f(s[3]);
        unsigned wa, wb;
        asm("v_cvt_pk_bf16_f32 %0, %1, %2" : "=v"(wa) : "v"(p0), "v"(p1));
        asm("v_cvt_pk_bf16_f32 %0, %1, %2" : "=v"(wb) : "v"(p2), "v"(p3));
        pw[b][blk*2+0] = wa;
        pw[b][blk*2+1] = wb;
      }
    }
    short8 af[2];
    #pragma unroll
    for (int b=0;b<2;b++){
      asm("v_permlane32_swap_b32 %0, %1" : "+v"(pw[b][0]), "+v"(pw[b][2]));
      asm("v_permlane32_swap_b32 %0, %1" : "+v"(pw[b][1]), "+v"(pw[b][3]));
      asm("v_permlane16_swap_b32 %0, %1" : "+v"(pw[b][0]), "+v"(pw[b][2]));
      asm("v_permlane16_swap_b32 %0, %1" : "+v"(pw[b][1]), "+v"(pw[b][3]));
      uint4v fw = { pw[b][0], pw[b][1], pw[b][2], pw[b][3] };
      af[b] = __builtin_bit_cast(short8, fw);
    }
    // ---- PV: O += P~.V~ for wave's q-half ----
    __builtin_amdgcn_s_setprio(1);
    #pragma unroll
    for (int dvb=0; dvb<8; ++dvb){
      int dv = dvb*16 + r15;
      short8 bv = *(const short8*)(Vb + dv*128 + (((qh*4 + g4)*16) ^ sw));
      acc[0][dvb] = __builtin_amdgcn_mfma_f32_16x16x32_bf16(af[0], bv, acc[0][dvb], 0, 0, 0);
      acc[1][dvb] = __builtin_amdgcn_mfma_f32_16x16x32_bf16(af[1], bv, acc[1][dvb], 0, 0, 0);
    }
    __builtin_amdgcn_s_setprio(0);
  }
  // ---- epilogue: reduce q-half pair via LDS, then atomics (qh=0 only) ----
  __syncthreads();                   // all waves done with buffers
  f32x4* red = (f32x4*)smem;         // [chunk 0..15][kg*64+lane] (conflict-free)
  if (qh == 1){
    #pragma unroll
    for (int b=0;b<2;b++)
      #pragma unroll
      for (int dvb=0; dvb<8; ++dvb)
        red[(b*8 + dvb)*256 + kg*64 + lane] = acc[b][dvb];
  }
  __syncthreads();
  if (qh == 0){
    #pragma unroll
    for (int b=0;b<2;b++)
      #pragma unroll
      for (int dvb=0; dvb<8; ++dvb){
        f32x4 o = red[(b*8 + dvb)*256 + kg*64 + lane];
        f32x4 a = acc[b][dvb];
        #pragma unroll
        for (int j=0;j<4;j++){
          int k  = ktile*128 + kg*32 + b*16 + g4*4 + j;
          int dv = dvb*16 + r15;
          atomicAdd(out + (size_t)k*DD + dv, a[j] + o[j]);
        }
      }
  }
}

extern "C" void kernel_launch(void* const* d_in, const int* in_sizes, int n_in,
                              void* d_out, int out_size, void* d_ws, size_t ws_size,
                              hipStream_t stream) {
  const float* Kp = (const float*)d_in[0];
  const float* Qp = (const float*)d_in[1];
  const float* Vp = (const float*)d_in[2];
  float* out = (float*)d_out;
  char* ws = (char*)d_ws;
  ushort_t* kws  = (ushort_t*)ws;
  ushort_t* qws  = (ushort_t*)(ws + ((size_t)2<<20));
  ushort_t* vtws = (ushort_t*)(ws + ((size_t)4<<20));
  float* zpart   = (float*)(ws + ((size_t)6<<20));

  hipMemsetAsync(d_out, 0, (size_t)SK*DD*sizeof(float), stream);
  prep_kq<<<dim3(1024), dim3(256), 0, stream>>>(Kp, Qp, kws, qws);
  kz     <<<dim3(1024), dim3(256), 0, stream>>>(kws, qws, zpart);
  prep_v <<<dim3(128),  dim3(256), 0, stream>>>(Vp, zpart, vtws);
  ko     <<<dim3(512),  dim3(512), 0, stream>>>(kws, qws, vtws, out);
}